// Round 6
// baseline (473.572 us; speedup 1.0000x reference)
//
#include <hip/hip_runtime.h>

#define HQ 32
#define HKV 8
#define DH 128
#define WIN 256
#define META 128
#define QSCALE 0.1275174324f    // rsqrt(128) * log2(e)  (scores in log2 space)
#define NFREQ 0.20762050594046f // log2(10000)/64
#define INV2PI 0.15915494309189535f

typedef __attribute__((ext_vector_type(8))) __bf16 bf16x8;
typedef __attribute__((ext_vector_type(4))) float f32x4;
typedef unsigned short u16;
typedef unsigned int u32;

__device__ __forceinline__ u16 f2bf(float f) {
  u32 u = __float_as_uint(f);
  u += 0x7FFFu + ((u >> 16) & 1u);
  return (u16)(u >> 16);
}
__device__ __forceinline__ u32 packbf(float a, float b) {  // a->lo16, b->hi16
  u32 ua = __float_as_uint(a); ua += 0x7FFFu + ((ua >> 16) & 1u);
  u32 ub = __float_as_uint(b); ub += 0x7FFFu + ((ub >> 16) & 1u);
  return (ua >> 16) | (ub & 0xFFFF0000u);
}
__device__ __forceinline__ void hw_sincos(float pos, float iv_rev, float* s, float* c) {
  float a = __builtin_amdgcn_fractf(pos * iv_rev);
  *s = __builtin_amdgcn_sinf(a);
  *c = __builtin_amdgcn_cosf(a);
}

// ---------- prep: RoPE(K) -> Kr[hk][s][d] bf16 ; V -> Vt[hk][d][s] bf16 ----------
__global__ __launch_bounds__(256)
void prep_kv(const float* __restrict__ Kg, const float* __restrict__ Vg,
             u16* __restrict__ Kr, u16* __restrict__ Vt, float2* __restrict__ Tab,
             int S) {
  __shared__ float T[32][132];
  const int hk = blockIdx.x;
  const int s0 = blockIdx.y * 32;
  const int tid = threadIdx.x;
  {
    const int r = tid >> 3, c0 = (tid & 7) * 8;
    const int s = s0 + r;
    const float pos = (float)s;
    const float* src = Kg + ((size_t)s * HKV + hk) * DH;
    u16* dst = Kr + ((size_t)hk * S + s) * DH;
    float x[8], y[8];
    #pragma unroll
    for (int j = 0; j < 8; j += 4) {
      *(float4*)&x[j] = *(const float4*)(src + c0 + j);
      *(float4*)&y[j] = *(const float4*)(src + c0 + 64 + j);
    }
    u16 lo[8], hb[8];
    #pragma unroll
    for (int j = 0; j < 8; ++j) {
      float iv = __builtin_amdgcn_exp2f(-NFREQ * (float)(c0 + j)) * INV2PI;
      float sv, cv; hw_sincos(pos, iv, &sv, &cv);
      if (hk == 0) Tab[(size_t)s * 64 + c0 + j] = make_float2(cv, sv);
      lo[j] = f2bf(x[j] * cv - y[j] * sv);
      hb[j] = f2bf(y[j] * cv + x[j] * sv);
    }
    *(int4*)(dst + c0)      = *(int4*)&lo[0];
    *(int4*)(dst + c0 + 64) = *(int4*)&hb[0];
  }
  {
    const int r = tid >> 3, c = (tid & 7) * 16;
    const float* src = Vg + ((size_t)(s0 + r) * HKV + hk) * DH + c;
    #pragma unroll
    for (int j = 0; j < 16; j += 4) *(float4*)&T[r][c + j] = *(const float4*)(src + j);
  }
  __syncthreads();
  {
    const int d = tid >> 1, hf = (tid & 1) * 16;
    u16 buf[16];
    #pragma unroll
    for (int i = 0; i < 16; ++i) buf[i] = f2bf(T[hf + i][d]);
    u16* dst = Vt + ((size_t)hk * DH + d) * S + s0 + hf;
    *(int4*)(dst)     = *(int4*)&buf[0];
    *(int4*)(dst + 8) = *(int4*)&buf[8];
  }
}

// ---- async global->LDS DMA, 16B per lane (dest = wave-uniform base + lane*16) ----
#define GLOAD16(gp_, lp_)                                                     \
  __builtin_amdgcn_global_load_lds(                                           \
      (const __attribute__((address_space(1))) void*)(gp_),                   \
      (__attribute__((address_space(3))) void*)(lp_), 16, 0, 0)

// Stage one 64-kv tile: K 64x256B + V 128x128B, 4+4 DMA instructions per wave.
// Source addrs are pre-swizzled (slot ^= row&7) so the linear LDS write yields
// the swizzled layout the MFMA fragment reads expect (G21: both-sides-or-neither).
#define STAGE(kv0_, kb_, vb_) do {                                            \
    const char* ks_ = KbC + (size_t)(kv0_) * 256;                             \
    GLOAD16(ks_ + kO0, (kb_) + wq);                                           \
    GLOAD16(ks_ + kO1, (kb_) + wq + 1024);                                    \
    GLOAD16(ks_ + kO2, (kb_) + wq + 2048);                                    \
    GLOAD16(ks_ + kO3, (kb_) + wq + 3072);                                    \
    const char* vs_ = VbC + (size_t)(kv0_) * 2;                               \
    GLOAD16(vs_ + vO0, (vb_) + wq);                                           \
    GLOAD16(vs_ + vO1, (vb_) + wq + 1024);                                    \
    GLOAD16(vs_ + vO2, (vb_) + wq + 2048);                                    \
    GLOAD16(vs_ + vO3, (vb_) + wq + 3072);                                    \
  } while (0)

// ---------- main: flash attention, S^T/O^T, 32 q-rows/wave, KVBLK=64 ----------
// 4 waves x 32q = 128 q-rows/block; grid 32x17 = 544 blocks.
// r5 post-mortem: occupancy pinned ~22% regardless of static cap -> latency-bound
// on the per-tile serial chain. This round amortizes it:
//  * 2 q-subtiles per wave: K/V LDS frags read ONCE, used twice; dual MFMA chains.
//  * DMA staging (global_load_lds): no staging VGPRs, no store burst.
//  * double-buffered K/V -> ONE barrier per tile (DMA overwrites the dead buffer;
//    syncthreads' vmcnt drain makes the next tile ready).
// LDS 81920 B: K0@0, K1@16K (64x256B), V0@32K, V1@48K (128x128B), P@64K (128x128B).
// 2 blocks/CU (160K exactly). Q prologue overlays K1||V1 (tile-0 DMA -> K0/V0).
__global__ __launch_bounds__(256)
void attn_main(const float* __restrict__ Qg, const u16* __restrict__ Kr,
               const u16* __restrict__ Vt, const float2* __restrict__ Tab,
               float* __restrict__ Og, int S) {
  extern __shared__ char smem[];
  const int h = blockIdx.x;
  const int nqb = gridDim.y;
  const int q0 = (nqb - 1 - (int)blockIdx.y) * 128;   // heavy blocks first
  const int hk = h >> 2;
  const int tid = threadIdx.x;
  const int lane = tid & 63;
  const int wave = tid >> 6;       // 0..3
  const int qid  = lane & 15;
  const int quad = lane >> 4;
  const int swz  = qid & 7;
  const int wq   = wave * 4096;    // per-wave DMA region offset (4KB per buffer)

  char* const K0 = smem;
  char* const K1 = smem + 16384;
  char* const V0 = smem + 32768;
  char* const V1 = smem + 49152;
  char* const Pb = smem + 65536;

  const char* KbC = (const char*)(Kr + (size_t)hk * S * DH);
  const char* VbC = (const char*)(Vt + (size_t)hk * DH * S);

  // per-lane pre-swizzled DMA source offsets
  const int krw = 16 * wave + (lane >> 4);        // K row for instr 0
  const int kO0 = (krw +  0) * 256 + (((lane & 15) ^ ((krw +  0) & 7)) << 4);
  const int kO1 = (krw +  4) * 256 + (((lane & 15) ^ ((krw +  4) & 7)) << 4);
  const int kO2 = (krw +  8) * 256 + (((lane & 15) ^ ((krw +  8) & 7)) << 4);
  const int kO3 = (krw + 12) * 256 + (((lane & 15) ^ ((krw + 12) & 7)) << 4);
  const int vrw = 32 * wave + (lane >> 3);        // V row (=d) for instr 0
  const int lV  = (((lane & 7) ^ ((lane >> 3) & 7)) << 4);
  const int vO0 = (vrw +  0) * (S * 2) + lV;
  const int vO1 = (vrw +  8) * (S * 2) + lV;
  const int vO2 = (vrw + 16) * (S * 2) + lV;
  const int vO3 = (vrw + 24) * (S * 2) + lV;

  STAGE(0, K0, V0);   // tile-0 DMA flies during the Q prologue

  // ---- prologue: 128 Q rows, table-RoPE * QSCALE, swizzled into K1 || V1 ----
  {
    const int rA = tid >> 2, a = tid & 3, c0 = a * 16;
    #pragma unroll
    for (int hlf = 0; hlf < 2; ++hlf) {
      const int r = rA + hlf * 64;
      const int s = q0 + r;
      const float* qrow = Qg + ((size_t)s * HQ + h) * DH + c0;
      const float2* tb = Tab + (size_t)s * 64 + c0;
      float x[16], y[16];
      float2 t[16];
      #pragma unroll
      for (int j = 0; j < 16; j += 4) {
        *(float4*)&x[j] = *(const float4*)(qrow + j);
        *(float4*)&y[j] = *(const float4*)(qrow + 64 + j);
      }
      #pragma unroll
      for (int j = 0; j < 16; j += 2) *(float4*)&t[j] = *(const float4*)(tb + j);
      u16 lo[16], hb[16];
      #pragma unroll
      for (int j = 0; j < 16; ++j) {
        lo[j] = f2bf((x[j] * t[j].x - y[j] * t[j].y) * QSCALE);
        hb[j] = f2bf((y[j] * t[j].x + x[j] * t[j].y) * QSCALE);
      }
      char* qd = (hlf ? V1 : K1) + rA * 256;
      *(int4*)(qd + (((2 * a)     ^ (r & 7)) << 4)) = *(int4*)&lo[0];
      *(int4*)(qd + (((2 * a + 1) ^ (r & 7)) << 4)) = *(int4*)&lo[8];
      *(int4*)(qd + (((2 * a + 8) ^ (r & 7)) << 4)) = *(int4*)&hb[0];
      *(int4*)(qd + (((2 * a + 9) ^ (r & 7)) << 4)) = *(int4*)&hb[8];
    }
  }
  __syncthreads();
  bf16x8 qa0[4], qa1[4];              // B-frags for the 2 q-subtiles
  {
    const char* qreg = (wave < 2) ? K1 : V1;
    const int lr = (wave & 1) * 32 + qid;
    const char* qb0 = qreg + lr * 256;
    const char* qb1 = qreg + (lr + 16) * 256;
    #pragma unroll
    for (int c = 0; c < 4; ++c) {
      qa0[c] = *(const bf16x8*)(qb0 + ((((c << 2) + quad) ^ swz) << 4));
      qa1[c] = *(const bf16x8*)(qb1 + ((((c << 2) + quad) ^ swz) << 4));
    }
  }
  __syncthreads();   // Q region dead -> K1/V1 become DMA targets

  const int qw0 = q0 + wave * 32;
  int wstart = q0 - WIN; if (wstart < META) wstart = META;
  int nwin = (q0 + 128 - wstart) >> 6; if (nwin < 0) nwin = 0;
  const int ntiles = 2 + nwin;        // 2 meta tiles first

  f32x4 acc0[8], acc1[8];
  #pragma unroll
  for (int D = 0; D < 8; ++D)
    #pragma unroll
    for (int r = 0; r < 4; ++r) { acc0[D][r] = 0.f; acc1[D][r] = 0.f; }
  float m0v = -1e30f, l0v = 0.f, m1v = -1e30f, l1v = 0.f;
  char* const Pw0 = Pb + (wave * 32 + qid) * 128;
  char* const Pw1 = Pw0 + 16 * 128;

  for (int t = 0; t < ntiles; ++t) {
    const int kv0 = (t < 2) ? t * 64 : wstart + (t - 2) * 64;
    if (t + 1 < ntiles) {             // DMA next tile into the dead buffer
      const int kvn = (t + 1 < 2) ? 64 : wstart + (t - 1) * 64;
      if ((t + 1) & 1) STAGE(kvn, K1, V1); else STAGE(kvn, K0, V0);
    }
    const char* Kc = (t & 1) ? K1 : K0;
    const char* Vc = (t & 1) ? V1 : V0;

    const bool act0 = (kv0 <= qw0 + 15) && ((kv0 < META) || (qw0 - kv0 - 63 <= WIN));
    const bool act1 = (kv0 <= qw0 + 31) && ((kv0 < META) || (qw0 + 16 - kv0 - 63 <= WIN));
    if (act0 || act1) {
      // ---- S^T = K Q^T : K frags read once, feed both q-subtiles ----
      f32x4 sv0[4], sv1[4];
      #pragma unroll
      for (int T = 0; T < 4; ++T)
        #pragma unroll
        for (int r = 0; r < 4; ++r) { sv0[T][r] = 0.f; sv1[T][r] = 0.f; }
      #pragma unroll
      for (int T = 0; T < 4; ++T) {
        const char* ka = Kc + (16 * T + qid) * 256;
        #pragma unroll
        for (int c = 0; c < 4; ++c) {
          const bf16x8 kf = *(const bf16x8*)(ka + ((((c << 2) + quad) ^ swz) << 4));
          if (act0) sv0[T] = __builtin_amdgcn_mfma_f32_16x16x32_bf16(kf, qa0[c], sv0[T], 0, 0, 0);
          if (act1) sv1[T] = __builtin_amdgcn_mfma_f32_16x16x32_bf16(kf, qa1[c], sv1[T], 0, 0, 0);
        }
      }

      bf16x8 p00, p01, p10, p11;
      // ---- q-subtile 0: mask + online softmax (defer-max) + P round-trip ----
      if (act0) {
        const int qu = qw0 + qid;
        const bool fullv = (kv0 + 63 <= qw0) && ((kv0 + 63 < META) || (qw0 + 15 - kv0 <= WIN));
        if (!fullv) {
          #pragma unroll
          for (int T = 0; T < 4; ++T)
            #pragma unroll
            for (int r = 0; r < 4; ++r) {
              const int kv = kv0 + 16 * T + 4 * quad + r;
              if (!((kv <= qu) && (((qu - kv) <= WIN) || (kv < META)))) sv0[T][r] = -1e30f;
            }
        }
        float mx = -1e30f;
        #pragma unroll
        for (int T = 0; T < 4; ++T)
          #pragma unroll
          for (int r = 0; r < 4; ++r) mx = fmaxf(mx, sv0[T][r]);
        mx = fmaxf(mx, __shfl_xor(mx, 16));
        mx = fmaxf(mx, __shfl_xor(mx, 32));
        if (!__all(mx - m0v <= 8.0f)) {
          const float mn = fmaxf(m0v, mx);
          const float al = __builtin_amdgcn_exp2f(m0v - mn);
          m0v = mn; l0v *= al;
          #pragma unroll
          for (int D = 0; D < 8; ++D)
            #pragma unroll
            for (int r = 0; r < 4; ++r) acc0[D][r] *= al;
        }
        float ps = 0.f;
        #pragma unroll
        for (int T = 0; T < 4; ++T)
          #pragma unroll
          for (int r = 0; r < 4; ++r) {
            sv0[T][r] = __builtin_amdgcn_exp2f(sv0[T][r] - m0v);
            ps += sv0[T][r];
          }
        l0v += ps;
        #pragma unroll
        for (int T = 0; T < 4; ++T) {
          int2 pr;
          pr.x = (int)packbf(sv0[T][0], sv0[T][1]);
          pr.y = (int)packbf(sv0[T][2], sv0[T][3]);
          *(int2*)(Pw0 + ((((T << 1) + (quad >> 1)) ^ swz) << 4) + ((quad & 1) << 3)) = pr;
        }
        p00 = *(const bf16x8*)(Pw0 + ((quad ^ swz) << 4));
        p01 = *(const bf16x8*)(Pw0 + (((4 + quad) ^ swz) << 4));
      }
      // ---- q-subtile 1 ----
      if (act1) {
        const int qw1 = qw0 + 16;
        const int qu = qw1 + qid;
        const bool fullv = (kv0 + 63 <= qw1) && ((kv0 + 63 < META) || (qw1 + 15 - kv0 <= WIN));
        if (!fullv) {
          #pragma unroll
          for (int T = 0; T < 4; ++T)
            #pragma unroll
            for (int r = 0; r < 4; ++r) {
              const int kv = kv0 + 16 * T + 4 * quad + r;
              if (!((kv <= qu) && (((qu - kv) <= WIN) || (kv < META)))) sv1[T][r] = -1e30f;
            }
        }
        float mx = -1e30f;
        #pragma unroll
        for (int T = 0; T < 4; ++T)
          #pragma unroll
          for (int r = 0; r < 4; ++r) mx = fmaxf(mx, sv1[T][r]);
        mx = fmaxf(mx, __shfl_xor(mx, 16));
        mx = fmaxf(mx, __shfl_xor(mx, 32));
        if (!__all(mx - m1v <= 8.0f)) {
          const float mn = fmaxf(m1v, mx);
          const float al = __builtin_amdgcn_exp2f(m1v - mn);
          m1v = mn; l1v *= al;
          #pragma unroll
          for (int D = 0; D < 8; ++D)
            #pragma unroll
            for (int r = 0; r < 4; ++r) acc1[D][r] *= al;
        }
        float ps = 0.f;
        #pragma unroll
        for (int T = 0; T < 4; ++T)
          #pragma unroll
          for (int r = 0; r < 4; ++r) {
            sv1[T][r] = __builtin_amdgcn_exp2f(sv1[T][r] - m1v);
            ps += sv1[T][r];
          }
        l1v += ps;
        #pragma unroll
        for (int T = 0; T < 4; ++T) {
          int2 pr;
          pr.x = (int)packbf(sv1[T][0], sv1[T][1]);
          pr.y = (int)packbf(sv1[T][2], sv1[T][3]);
          *(int2*)(Pw1 + ((((T << 1) + (quad >> 1)) ^ swz) << 4) + ((quad & 1) << 3)) = pr;
        }
        p10 = *(const bf16x8*)(Pw1 + ((quad ^ swz) << 4));
        p11 = *(const bf16x8*)(Pw1 + (((4 + quad) ^ swz) << 4));
      }

      // ---- O^T += V^T P^T : V frags read once, feed both q-subtiles ----
      #pragma unroll
      for (int D = 0; D < 8; ++D) {
        const char* va = Vc + (16 * D + qid) * 128;
        const bf16x8 v0f = *(const bf16x8*)(va + ((quad ^ swz) << 4));
        const bf16x8 v1f = *(const bf16x8*)(va + (((4 + quad) ^ swz) << 4));
        if (act0) {
          acc0[D] = __builtin_amdgcn_mfma_f32_16x16x32_bf16(v0f, p00, acc0[D], 0, 0, 0);
          acc0[D] = __builtin_amdgcn_mfma_f32_16x16x32_bf16(v1f, p01, acc0[D], 0, 0, 0);
        }
        if (act1) {
          acc1[D] = __builtin_amdgcn_mfma_f32_16x16x32_bf16(v0f, p10, acc1[D], 0, 0, 0);
          acc1[D] = __builtin_amdgcn_mfma_f32_16x16x32_bf16(v1f, p11, acc1[D], 0, 0, 0);
        }
      }
    }
    __syncthreads();   // drains DMA (next tile ready) + all waves done with cur
  }

  // ---- epilogue ----
  l0v += __shfl_xor(l0v, 16); l0v += __shfl_xor(l0v, 32);
  l1v += __shfl_xor(l1v, 16); l1v += __shfl_xor(l1v, 32);
  const float inv0 = 1.0f / l0v;
  const float inv1 = 1.0f / l1v;
  float* ob0 = Og + ((size_t)(qw0 + qid) * HQ + h) * DH;
  float* ob1 = Og + ((size_t)(qw0 + 16 + qid) * HQ + h) * DH;
  #pragma unroll
  for (int D = 0; D < 8; ++D) {
    float4 o0 = { acc0[D][0] * inv0, acc0[D][1] * inv0, acc0[D][2] * inv0, acc0[D][3] * inv0 };
    float4 o1 = { acc1[D][0] * inv1, acc1[D][1] * inv1, acc1[D][2] * inv1, acc1[D][3] * inv1 };
    *(float4*)(ob0 + 16 * D + 4 * quad) = o0;
    *(float4*)(ob1 + 16 * D + 4 * quad) = o1;
  }
}

extern "C" void kernel_launch(void* const* d_in, const int* in_sizes, int n_in,
                              void* d_out, int out_size, void* d_ws, size_t ws_size,
                              hipStream_t stream) {
  const float* Qg = (const float*)d_in[0];
  const float* Kg = (const float*)d_in[1];
  const float* Vg = (const float*)d_in[2];
  float* Og = (float*)d_out;
  const int S = in_sizes[0] / (HQ * DH);   // 2176

  u16* Kr = (u16*)d_ws;                                            // 4.45 MB
  u16* Vt = (u16*)((char*)d_ws + (size_t)HKV * S * DH * 2);        // 4.45 MB
  float2* Tab = (float2*)((char*)d_ws + (size_t)HKV * S * DH * 4); // 1.11 MB cos/sin

  static bool attr_done = false;
  if (!attr_done) {
    (void)hipFuncSetAttribute((const void*)attn_main,
                              hipFuncAttributeMaxDynamicSharedMemorySize, 81920);
    attr_done = true;
  }

  prep_kv<<<dim3(HKV, S / 32), dim3(256), 0, stream>>>(Kg, Vg, Kr, Vt, Tab, S);
  attn_main<<<dim3(HQ, S / 128), dim3(256), 81920, stream>>>(Qg, Kr, Vt, Tab, Og, S);
}

// Round 8
// 135.024 us; speedup vs baseline: 3.5073x; 3.5073x over previous
//
#include <hip/hip_runtime.h>

#define HQ 32
#define HKV 8
#define DH 128
#define WIN 256
#define META 128
#define QSCALE 0.1275174324f    // rsqrt(128) * log2(e)  (scores produced in log2 space)
#define NFREQ 0.20762050594046f // log2(10000)/64: invfreq(i) = exp2(-NFREQ*i)
#define INV2PI 0.15915494309189535f

typedef __attribute__((ext_vector_type(8))) __bf16 bf16x8;
typedef __attribute__((ext_vector_type(4))) float f32x4;
typedef unsigned short u16;
typedef unsigned int u32;

__device__ __forceinline__ u16 f2bf(float f) {
  u32 u = __float_as_uint(f);
  u += 0x7FFFu + ((u >> 16) & 1u);
  return (u16)(u >> 16);
}
__device__ __forceinline__ u32 packbf(float a, float b) {  // a->lo16, b->hi16
  u32 ua = __float_as_uint(a); ua += 0x7FFFu + ((ua >> 16) & 1u);
  u32 ub = __float_as_uint(b); ub += 0x7FFFu + ((ub >> 16) & 1u);
  return (ua >> 16) | (ub & 0xFFFF0000u);
}
// HW trig: v_sin/v_cos take REVOLUTIONS; reduce with v_fract.
// angle error ~1.3e-4 rad << bf16 quantization 4e-3. (validated r3/r5)
__device__ __forceinline__ void hw_sincos(float pos, float iv_rev, float* s, float* c) {
  float a = __builtin_amdgcn_fractf(pos * iv_rev);
  *s = __builtin_amdgcn_sinf(a);
  *c = __builtin_amdgcn_cosf(a);
}

// ---------- prep: RoPE(K) -> Kr[hk][s][d] bf16 ; V -> Vt[hk][d][s] bf16 ----------
// hk==0 blocks also emit the cos/sin table (f32x2 [s][64]) for attn's Q RoPE.
__global__ __launch_bounds__(256)
void prep_kv(const float* __restrict__ Kg, const float* __restrict__ Vg,
             u16* __restrict__ Kr, u16* __restrict__ Vt, float2* __restrict__ Tab,
             int S) {
  __shared__ float T[32][132];
  const int hk = blockIdx.x;
  const int s0 = blockIdx.y * 32;
  const int tid = threadIdx.x;
  {
    const int r = tid >> 3, c0 = (tid & 7) * 8;
    const int s = s0 + r;
    const float pos = (float)s;
    const float* src = Kg + ((size_t)s * HKV + hk) * DH;
    u16* dst = Kr + ((size_t)hk * S + s) * DH;
    float x[8], y[8];
    #pragma unroll
    for (int j = 0; j < 8; j += 4) {
      *(float4*)&x[j] = *(const float4*)(src + c0 + j);
      *(float4*)&y[j] = *(const float4*)(src + c0 + 64 + j);
    }
    u16 lo[8], hb[8];
    #pragma unroll
    for (int j = 0; j < 8; ++j) {
      float iv = __builtin_amdgcn_exp2f(-NFREQ * (float)(c0 + j)) * INV2PI;
      float sv, cv; hw_sincos(pos, iv, &sv, &cv);
      if (hk == 0) Tab[(size_t)s * 64 + c0 + j] = make_float2(cv, sv);
      lo[j] = f2bf(x[j] * cv - y[j] * sv);
      hb[j] = f2bf(y[j] * cv + x[j] * sv);
    }
    *(int4*)(dst + c0)      = *(int4*)&lo[0];
    *(int4*)(dst + c0 + 64) = *(int4*)&hb[0];
  }
  {
    const int r = tid >> 3, c = (tid & 7) * 16;
    const float* src = Vg + ((size_t)(s0 + r) * HKV + hk) * DH + c;
    #pragma unroll
    for (int j = 0; j < 16; j += 4) *(float4*)&T[r][c + j] = *(const float4*)(src + j);
  }
  __syncthreads();
  {
    const int d = tid >> 1, hf = (tid & 1) * 16;
    u16 buf[16];
    #pragma unroll
    for (int i = 0; i < 16; ++i) buf[i] = f2bf(T[hf + i][d]);
    u16* dst = Vt + ((size_t)hk * DH + d) * S + s0 + hf;
    *(int4*)(dst)     = *(int4*)&buf[0];
    *(int4*)(dst + 8) = *(int4*)&buf[8];
  }
}

// Register prefetch of next KV tile. NAMED scalars (no arrays/lambdas: alloca trap).
#define LOAD_KV(kv0_) do {                                                 \
    const int4* ks_ = (const int4*)(Kb + (size_t)((kv0_) + kr) * DH + kc); \
    fk0 = ks_[0]; fk1 = ks_[1]; fk2 = ks_[2]; fk3 = ks_[3];                \
    const int4* vs_ = (const int4*)(Vb + (kv0_));                          \
    fv0 = vs_[0]; fv1 = vs_[1]; fv2 = vs_[2]; fv3 = vs_[3];                \
  } while (0)

#define STORE_KV() do {                                                    \
    int4* kd_ = (int4*)&Ks[kr][kc];                                        \
    kd_[0] = fk0; kd_[1] = fk1; kd_[2] = fk2; kd_[3] = fk3;                \
    int4* vd_ = (int4*)&Vs[tid >> 1][(tid & 1) * 32];                      \
    vd_[0] = fv0; vd_[1] = fv1; vd_[2] = fv2; vd_[3] = fv3;                \
  } while (0)

// ---------- main: flash attention, S^T/O^T, 16 q-rows per wave (16x16x32 MFMA) ----------
// EXACT r0 structure (best measured: 45.3us attn): 4 waves/64q, KVBLK=64, padded LDS
// 45056B (3 blocks/CU), reg-staged prefetch, 2 barriers/tile, (256,3).
// Additions (each individually validated r3/r5, none touch hot-loop addressing):
//  * defer-max (T13): skip O-rescale while __all(mx - m_i <= 8) (log2-space scores;
//    P bounded by 2^8, bf16 relative error scale-free).
//  * table-RoPE prologue (cos/sin from Tab; kills 16 libm sincos/thread).
//  * P C->B transform via int2 (b64) writes.
__global__ __launch_bounds__(256, 3)
void attn_main(const float* __restrict__ Qg, const u16* __restrict__ Kr,
               const u16* __restrict__ Vt, const float2* __restrict__ Tab,
               float* __restrict__ Og, int S) {
  const int h = blockIdx.x;
  const int nqb = gridDim.y;
  const int q0 = (nqb - 1 - (int)blockIdx.y) * 64;   // heavy blocks first
  const int hk = h >> 2;
  const int tid = threadIdx.x;
  const int lane = tid & 63;
  const int wave = tid >> 6;
  const int qid  = lane & 15;      // q col within wave tile (C/D n-index)
  const int quad = lane >> 4;      // 0..3
  const int k8   = quad * 8;       // A/B-frag k offset within a 32-chunk

  // Overlay: prologue Qs[64][136] (17408 B); loop Ks 17408 + Vs 18432 + Ps 9216 = 45056 B
  __shared__ __align__(16) char smem[45056];
  u16 (*Qs)[136] = (u16(*)[136])smem;
  u16 (*Ks)[136] = (u16(*)[136])smem;
  u16 (*Vs)[72]  = (u16(*)[72])(smem + 17408);
  u16 (*Ps)[72]  = (u16(*)[72])(smem + 35840);   // row = wave*16 + q

  const u16* Kb = Kr + (size_t)hk * S * DH;
  const u16* Vb = Vt + ((size_t)hk * DH + (tid >> 1)) * S + (tid & 1) * 32;
  const int kr = tid >> 2, kc = (tid & 3) * 32;

  int4 fk0, fk1, fk2, fk3, fv0, fv1, fv2, fv3;
  LOAD_KV(0);   // tile-0 loads fly during the Q prologue

  // ---- prologue: stage Q (64 rows) with table-RoPE * QSCALE ----
  {
    const int r = tid >> 2, c0 = (tid & 3) * 16;
    const int s = q0 + r;
    const float* qrow = Qg + ((size_t)s * HQ + h) * DH;
    const float2* tb = Tab + (size_t)s * 64 + c0;
    float x[16], y[16];
    float2 t[16];
    #pragma unroll
    for (int j = 0; j < 16; j += 4) {
      *(float4*)&x[j] = *(const float4*)(qrow + c0 + j);
      *(float4*)&y[j] = *(const float4*)(qrow + c0 + 64 + j);
    }
    #pragma unroll
    for (int j = 0; j < 16; j += 2) *(float4*)&t[j] = *(const float4*)(tb + j);
    u16 lo[16], hb[16];
    #pragma unroll
    for (int j = 0; j < 16; ++j) {
      lo[j] = f2bf((x[j] * t[j].x - y[j] * t[j].y) * QSCALE);
      hb[j] = f2bf((y[j] * t[j].x + x[j] * t[j].y) * QSCALE);
    }
    *(int4*)(&Qs[r][c0])      = *(int4*)&lo[0];
    *(int4*)(&Qs[r][c0 + 8])  = *(int4*)&lo[8];
    *(int4*)(&Qs[r][c0 + 64]) = *(int4*)&hb[0];
    *(int4*)(&Qs[r][c0 + 72]) = *(int4*)&hb[8];
  }
  __syncthreads();
  const int qw0 = q0 + wave * 16;
  const int q   = qw0 + qid;          // this lane's q row
  bf16x8 qa[4];                       // B-frags: Q[q][32c + k8 + j]
  {
    const u16* qb = &Qs[wave * 16 + qid][k8];
    #pragma unroll
    for (int c = 0; c < 4; ++c) qa[c] = *(const bf16x8*)(qb + 32 * c);
  }
  __syncthreads();   // Qs dead; region becomes Ks/Vs
  STORE_KV();        // tile 0 -> LDS
  __syncthreads();

  int wstart = q0 - WIN; if (wstart < META) wstart = META;
  int nwin = (q0 + 64 - wstart) >> 6; if (nwin < 0) nwin = 0;
  const int ntiles = 2 + nwin;        // meta tiles first

  f32x4 acc[8];                       // O^T: acc[D], d = 16D + 4*quad + r, col q
  #pragma unroll
  for (int D = 0; D < 8; ++D)
    #pragma unroll
    for (int r = 0; r < 4; ++r) acc[D][r] = 0.f;
  float m_i = -1e30f, l_i = 0.f;      // l_i is a quad-partial; combined in epilogue

  for (int t = 0; t < ntiles; ++t) {
    const int kv0 = (t < 2) ? t * 64 : wstart + (t - 2) * 64;
    const bool haveNext = (t + 1 < ntiles);
    if (haveNext) {
      const int kvn = (t + 1 < 2) ? (t + 1) * 64 : wstart + (t - 1) * 64;
      LOAD_KV(kvn);
    }

    const bool active = (kv0 <= qw0 + 15) &&
                        ((kv0 < META) || (qw0 - kv0 - 63 <= WIN));
    if (active) {
      // ---- S^T = K Q^T : 4 16x16 C-tiles over kv, K=128 in 4 chunks ----
      f32x4 sv[4];
      #pragma unroll
      for (int T = 0; T < 4; ++T)
        #pragma unroll
        for (int r = 0; r < 4; ++r) sv[T][r] = 0.f;
      #pragma unroll
      for (int T = 0; T < 4; ++T) {
        const u16* ka = &Ks[16 * T + qid][k8];
        #pragma unroll
        for (int c = 0; c < 4; ++c)
          sv[T] = __builtin_amdgcn_mfma_f32_16x16x32_bf16(
                    *(const bf16x8*)(ka + 32 * c), qa[c], sv[T], 0, 0, 0);
      }

      // ---- mask (per element: kv = kv0 + 16T + 4*quad + r) ----
      const bool fullv = (kv0 + 63 <= qw0) &&
                         ((kv0 + 63 < META) || (qw0 + 15 - kv0 <= WIN));
      if (!fullv) {
        #pragma unroll
        for (int T = 0; T < 4; ++T) {
          #pragma unroll
          for (int r = 0; r < 4; ++r) {
            const int kv = kv0 + 16 * T + 4 * quad + r;
            if (!((kv <= q) && (((q - kv) <= WIN) || (kv < META)))) sv[T][r] = -1e30f;
          }
        }
      }

      // ---- online softmax: reg reduce + 2 cross-quad shuffles for max ----
      float mx = -1e30f;
      #pragma unroll
      for (int T = 0; T < 4; ++T)
        #pragma unroll
        for (int r = 0; r < 4; ++r) mx = fmaxf(mx, sv[T][r]);
      mx = fmaxf(mx, __shfl_xor(mx, 16));
      mx = fmaxf(mx, __shfl_xor(mx, 32));
      // defer-max (T13): rescale only when some row's max grew past 2^8 headroom
      if (!__all(mx - m_i <= 8.0f)) {
        const float mnew = fmaxf(m_i, mx);
        const float al = __builtin_amdgcn_exp2f(m_i - mnew);
        m_i = mnew;
        l_i *= al;
        #pragma unroll
        for (int D = 0; D < 8; ++D)
          #pragma unroll
          for (int r = 0; r < 4; ++r) acc[D][r] *= al;
      }
      float ps = 0.f;
      #pragma unroll
      for (int T = 0; T < 4; ++T)
        #pragma unroll
        for (int r = 0; r < 4; ++r) {
          sv[T][r] = __builtin_amdgcn_exp2f(sv[T][r] - m_i);
          ps += sv[T][r];
        }
      l_i += ps;                      // quad-partial sum (m shared => consistent)

      // ---- P: C-layout -> B-layout via wave-private LDS (in-order, no barrier) ----
      {
        int2* pw = (int2*)&Ps[wave * 16 + qid][0];
        #pragma unroll
        for (int T = 0; T < 4; ++T) {
          int2 pr;
          pr.x = (int)packbf(sv[T][0], sv[T][1]);
          pr.y = (int)packbf(sv[T][2], sv[T][3]);
          pw[4 * T + quad] = pr;
        }
      }
      const u16* pb = &Ps[wave * 16 + qid][k8];
      const bf16x8 p0 = *(const bf16x8*)(pb);        // kv chunk 0 (0..31)
      const bf16x8 p1 = *(const bf16x8*)(pb + 32);   // kv chunk 1 (32..63)

      // ---- O^T += V^T P^T : 8 d-tiles x 2 kv-chunks ----
      #pragma unroll
      for (int D = 0; D < 8; ++D) {
        const u16* va = &Vs[16 * D + qid][k8];
        acc[D] = __builtin_amdgcn_mfma_f32_16x16x32_bf16(*(const bf16x8*)(va),      p0, acc[D], 0, 0, 0);
        acc[D] = __builtin_amdgcn_mfma_f32_16x16x32_bf16(*(const bf16x8*)(va + 32), p1, acc[D], 0, 0, 0);
      }
    }

    if (haveNext) {
      __syncthreads();   // all waves done reading Ks/Vs
      STORE_KV();        // prefetched tile -> LDS
      __syncthreads();
    }
  }

  // ---- epilogue: combine quad-partial l, scale, 16B stores ----
  l_i += __shfl_xor(l_i, 16);
  l_i += __shfl_xor(l_i, 32);
  const float inv = 1.0f / l_i;
  float* ob = Og + ((size_t)q * HQ + h) * DH;
  #pragma unroll
  for (int D = 0; D < 8; ++D) {       // d = 16D + 4*quad + {0..3}
    float4 o = { acc[D][0] * inv, acc[D][1] * inv, acc[D][2] * inv, acc[D][3] * inv };
    *(float4*)(ob + 16 * D + 4 * quad) = o;
  }
}

extern "C" void kernel_launch(void* const* d_in, const int* in_sizes, int n_in,
                              void* d_out, int out_size, void* d_ws, size_t ws_size,
                              hipStream_t stream) {
  const float* Qg = (const float*)d_in[0];
  const float* Kg = (const float*)d_in[1];
  const float* Vg = (const float*)d_in[2];
  float* Og = (float*)d_out;
  const int S = in_sizes[0] / (HQ * DH);   // 2176

  u16* Kr = (u16*)d_ws;                                            // 4.45 MB
  u16* Vt = (u16*)((char*)d_ws + (size_t)HKV * S * DH * 2);        // 4.45 MB
  float2* Tab = (float2*)((char*)d_ws + (size_t)HKV * S * DH * 4); // 1.11 MB cos/sin table

  prep_kv<<<dim3(HKV, S / 32), dim3(256), 0, stream>>>(Kg, Vg, Kr, Vt, Tab, S);
  attn_main<<<dim3(HQ, S / 64), dim3(256), 0, stream>>>(Qg, Kr, Vt, Tab, Og, S);
}